// Round 9
// baseline (324.389 us; speedup 1.0000x reference)
//
#include <hip/hip_runtime.h>
#include <hip/hip_cooperative_groups.h>
#include <math.h>

namespace cg = cooperative_groups;

#define W 1024
#define H 768
#define PIX (W*H)          // 786432
#define NIMG 4
#define SNUM 131072
#define BPI 3072           // 256-pixel units per image
#define UPB 12             // units per prep block
#define FPB 1024           // prep blocks (256/image, 4/CU -> safely co-resident)
#define MASKV (-1e-8f)

__device__ __forceinline__ void sobel_g(const float* __restrict__ img, int y, int x,
                                        float& gx, float& gy) {
    const float* r0 = img + (y - 1) * W + x;
    const float* r1 = r0 + W;
    const float* r2 = r1 + W;
    float a00 = r0[-1], a01 = r0[0], a02 = r0[1];
    float a10 = r1[-1],              a12 = r1[1];
    float a20 = r2[-1], a21 = r2[0], a22 = r2[1];
    gx = (a02 - a00) + 2.f * (a12 - a10) + (a22 - a20);
    gy = (a00 - a20) + 2.f * (a01 - a21) + (a02 - a22);
}

// ---------- Phase A: Sobel e/theta (->LDS if given), pack pairIT, segmented compV ----------
__device__ void phaseA(const float* __restrict__ inputs, const float* __restrict__ targets,
                       const float* __restrict__ images,
                       float2* __restrict__ pairIT, int* __restrict__ compVSeg,
                       float* __restrict__ blockmax, int* __restrict__ blkV,
                       float* sE, float* sTh)   // LDS (may be null in fallback path A? no: A always has them or writes nothing)
{
    __shared__ float sRed[256];
    __shared__ int sW[4];
    int blk = blockIdx.x, t = threadIdx.x;
    int i = blk >> 8, bb = blk & 255;
    const float* img = images + (size_t)i * 3 * PIX;   // channel 0
    int lane = t & 63, w = t >> 6;
    unsigned long long lm = (1ull << lane) - 1ull;

    float bmax = 0.f;
    for (int k = 0; k < UPB; k++) {
        int unit = bb * UPB + k;
        int gp = unit * 256 + t;
        int y = gp >> 10, x = gp & (W - 1);
        float e = 0.f, th = 0.f;
        if (y >= 1 && y <= H - 2 && x >= 1 && x <= W - 2) {
            float gx, gy;
            sobel_g(img, y, x, gx, gy);
            e = sqrtf(gx * gx + gy * gy);
            th = atan2f(gy, gx);
        }
        if (sE) { sE[k * 256 + t] = e; sTh[k * 256 + t] = th; }
        bmax = fmaxf(bmax, e);
        size_t off = (size_t)i * PIX + gp;
        float inv = inputs[off], tgv = targets[off];
        pairIT[off] = make_float2(inv, tgv);
        bool v = tgv > MASKV;
        unsigned long long mV = __ballot(v);
        __syncthreads();                          // protect sW reuse across iterations
        if (lane == 0) sW[w] = __popcll(mV);
        __syncthreads();
        int base = 0;
        for (int q = 0; q < w; q++) base += sW[q];
        if (t == 0) blkV[i * BPI + unit] = sW[0] + sW[1] + sW[2] + sW[3];
        if (v) compVSeg[(size_t)i * PIX + unit * 256 + base + __popcll(mV & lm)] = gp;
    }
    __syncthreads();
    sRed[t] = bmax;
    __syncthreads();
    for (int o = 128; o > 0; o >>= 1) {
        if (t < o) sRed[t] = fmaxf(sRed[t], sRed[t + o]);
        __syncthreads();
    }
    if (t == 0) blockmax[blk] = sRed[0];
}

// ---------- Phase B: thr reduce + segmented edge compaction + blkV scan ----------
__device__ void phaseB(const float* __restrict__ images,
                       const float* __restrict__ blockmax, const int* __restrict__ blkV,
                       float2* __restrict__ anchorSeg, int* __restrict__ cntE,
                       int* __restrict__ SVg, int* __restrict__ vtotG,
                       const float* sE, const float* sTh)  // null -> recompute Sobel
{
    __shared__ float sRed2[256];
    __shared__ int sW2[4];
    int blk = blockIdx.x, t = threadIdx.x;
    int i = blk >> 8, bb = blk & 255;
    const float* img = images + (size_t)i * 3 * PIX;
    int lane = t & 63, w = t >> 6;
    unsigned long long lm = (1ull << lane) - 1ull;

    const float* bm = blockmax + i * 256;         // redundant per-image max reduce
    sRed2[t] = bm[t];
    __syncthreads();
    for (int o = 128; o > 0; o >>= 1) {
        if (t < o) sRed2[t] = fmaxf(sRed2[t], sRed2[t + o]);
        __syncthreads();
    }
    float thr = 0.1f * sRed2[0];

    for (int k = 0; k < UPB; k++) {
        int unit = bb * UPB + k;
        int gp = unit * 256 + t;
        float e, th;
        if (sE) {
            e = sE[k * 256 + t]; th = sTh[k * 256 + t];
        } else {
            int y = gp >> 10, x = gp & (W - 1);
            e = 0.f; th = 0.f;
            if (y >= 1 && y <= H - 2 && x >= 1 && x <= W - 2) {
                float gx, gy;
                sobel_g(img, y, x, gx, gy);
                e = sqrtf(gx * gx + gy * gy);
                th = atan2f(gy, gx);
            }
        }
        bool isE = (e >= thr);                    // border e=0: matches padded ref
        unsigned long long mE = __ballot(isE);
        __syncthreads();
        if (lane == 0) sW2[w] = __popcll(mE);
        __syncthreads();
        int base = 0;
        for (int q = 0; q < w; q++) base += sW2[q];
        if (t == 0) cntE[i * BPI + unit] = sW2[0] + sW2[1] + sW2[2] + sW2[3];
        if (isE)
            anchorSeg[(size_t)i * PIX + unit * 256 + base + __popcll(mE & lm)] =
                make_float2(__int_as_float(gp), th);
    }

    if (bb == 0) {                                // per-image blkV scan -> SVg, vtotG
        __syncthreads();
        __shared__ int sT[256];
        const int* bv = blkV + i * BPI;
        int loc[12]; int tot = 0;
#pragma unroll
        for (int k = 0; k < 12; k++) { loc[k] = bv[t * 12 + k]; tot += loc[k]; }
        sT[t] = tot;
        __syncthreads();
        for (int o = 1; o < 256; o <<= 1) {
            int v = (t >= o) ? sT[t - o] : 0;
            __syncthreads();
            sT[t] += v;
            __syncthreads();
        }
        int run = sT[t] - tot;
        int* sv = SVg + i * BPI;
#pragma unroll
        for (int k = 0; k < 12; k++) { sv[t * 12 + k] = run; run += loc[k]; }
        if (t == 255) vtotG[i] = sT[255];
    }
}

// ---- fused cooperative: A | grid.sync | B (theta reused from LDS) ----
__global__ __launch_bounds__(256, 4) void fused_prep(
    const float* __restrict__ inputs, const float* __restrict__ targets,
    const float* __restrict__ images,
    float2* __restrict__ pairIT,
    float* __restrict__ blockmax, int* __restrict__ blkV, int* __restrict__ cntE,
    float2* __restrict__ anchorSeg, int* __restrict__ compVSeg,
    int* __restrict__ SVg, int* __restrict__ vtotG)
{
    cg::grid_group grid = cg::this_grid();
    __shared__ float sE[UPB * 256];               // 12KB
    __shared__ float sTh[UPB * 256];              // 12KB
    phaseA(inputs, targets, images, pairIT, compVSeg, blockmax, blkV, sE, sTh);
    grid.sync();                                  // the only grid-wide dependency: emax
    phaseB(images, blockmax, blkV, anchorSeg, cntE, SVg, vtotG, sE, sTh);
}

// ---- fallback (plain) kernels: identical math, Sobel recomputed in B ----
__global__ void prepA_kernel(const float* __restrict__ inputs,
                             const float* __restrict__ targets,
                             const float* __restrict__ images,
                             float2* __restrict__ pairIT, int* __restrict__ compVSeg,
                             float* __restrict__ blockmax, int* __restrict__ blkV) {
    phaseA(inputs, targets, images, pairIT, compVSeg, blockmax, blkV, nullptr, nullptr);
}
__global__ void prepB_kernel(const float* __restrict__ images,
                             const float* __restrict__ blockmax, const int* __restrict__ blkV,
                             float2* __restrict__ anchorSeg, int* __restrict__ cntE,
                             int* __restrict__ SVg, int* __restrict__ vtotG) {
    phaseB(images, blockmax, blkV, anchorSeg, cntE, SVg, vtotG, nullptr, nullptr);
}

// ---- loss (round-7 verbatim: LDS scan of cntE + binary search; no atomics/fences) ----
__device__ __forceinline__ void pair_term(float2 a, float2 b, float& eqs, float& uns) {
    float cm = ((a.y > MASKV) ? 1.f : 0.f) * ((b.y > MASKV) ? 1.f : 0.f);
    float ratio = (a.y + 1e-6f) / (b.y + 1e-6f);
    const float HIv = 1.03f;
    const float LOv = (float)(1.0 / 1.03);
    bool eq = (ratio < HIv) && (ratio > LOv);
    if (eq) {
        float d = a.x - b.x;
        eqs += d * d * cm;
    } else {
        float label = ((ratio >= HIv) ? 1.f : 0.f) + ((ratio <= LOv) ? -1.f : 0.f);
        uns += log1pf(expf((b.x - a.x) * label)) * cm;
    }
}

__global__ void loss_kernel(const float2* __restrict__ pairIT,
                            const float2* __restrict__ anchorSeg,
                            const int* __restrict__ compVSeg,
                            const int* __restrict__ cntE,
                            const int* __restrict__ SVg,
                            const int* __restrict__ vtotG,
                            const int* __restrict__ ra, const int* __restrict__ rd,
                            const int* __restrict__ rp,
                            float2* __restrict__ partials) {
    int i = blockIdx.y, t = threadIdx.x;
    __shared__ int S[BPI];                       // 12KB: exclusive scan of cntE
    __shared__ int sT[256];
    {
        const int* ce = cntE + i * BPI;
        int loc[12]; int tot = 0;
#pragma unroll
        for (int k = 0; k < 12; k++) { loc[k] = ce[t * 12 + k]; tot += loc[k]; }
        sT[t] = tot;
        __syncthreads();
        for (int o = 1; o < 256; o <<= 1) {
            int v = (t >= o) ? sT[t - o] : 0;
            __syncthreads();
            sT[t] += v;
            __syncthreads();
        }
        int run = sT[t] - tot;
#pragma unroll
        for (int k = 0; k < 12; k++) { S[t * 12 + k] = run; run += loc[k]; }
        __syncthreads();
    }
    int eT = sT[255];                            // etot; >=1 always (emax passes thr)
    int vT = vtotG[i];
    int nval = (vT > 0) ? vT : 1;

    int s = blockIdx.x * 256 + t;
    const float2* pIT = pairIT + (size_t)i * PIX;

    int j = ra[(size_t)i * SNUM + s] % eT;
    int lo = 0, hi = BPI - 1;                    // largest b with S[b] <= j
#pragma unroll
    for (int k = 0; k < 12; k++) {
        int mid = (lo + hi + 1) >> 1;
        if (S[mid] <= j) lo = mid; else hi = mid - 1;
    }
    float2 ac = anchorSeg[(size_t)i * PIX + lo * 256 + (j - S[lo])];
    int anchor = __float_as_int(ac.x);
    float sv = sinf(ac.y), cv = cosf(ac.y);
    int row_a = anchor >> 10, col_a = anchor & (W - 1);

    int pix4[4];
#pragma unroll
    for (int k = 0; k < 4; k++) {
        int r = rd[((size_t)i * 4 + k) * SNUM + s];
        float dist = ((float)r + 2.0f) * ((k < 2) ? -1.f : 1.f);
        int cc = col_a + (int)rintf(dist * cv);  // round-half-even = jnp.round
        int rr = row_a + (int)rintf(dist * sv);
        cc = min(max(cc, 0), W - 1);
        rr = min(max(rr, 0), H - 1);
        pix4[k] = (rr << 10) | cc;
    }
    int2 rr2 = *(const int2*)(rp + (size_t)i * 2 * SNUM + 2 * s);
    int r0 = rr2.x % nval, r1 = rr2.y % nval;
    int A, B;
    if ((vT == PIX) || (vT == 0)) {              // identity compaction cases
        A = r0; B = r1;
    } else {
        const int* SV = SVg + i * BPI;
        int lo2 = 0, hi2 = BPI - 1;
        int lo3 = 0, hi3 = BPI - 1;
#pragma unroll
        for (int k = 0; k < 12; k++) {
            int m2 = (lo2 + hi2 + 1) >> 1;
            if (SV[m2] <= r0) lo2 = m2; else hi2 = m2 - 1;
            int m3 = (lo3 + hi3 + 1) >> 1;
            if (SV[m3] <= r1) lo3 = m3; else hi3 = m3 - 1;
        }
        A = compVSeg[(size_t)i * PIX + lo2 * 256 + (r0 - SV[lo2])];
        B = compVSeg[(size_t)i * PIX + lo3 * 256 + (r1 - SV[lo3])];
    }

    float2 a0 = pIT[pix4[0]], a1 = pIT[pix4[1]], a2 = pIT[pix4[2]], a3 = pIT[pix4[3]];
    float2 b0 = pIT[A], b1 = pIT[B];
    float eqs = 0.f, uns = 0.f;
    pair_term(a0, a1, eqs, uns);
    pair_term(a1, a2, eqs, uns);
    pair_term(a2, a3, eqs, uns);
    pair_term(b0, b1, eqs, uns);

    __shared__ float sEq[256], sUn[256];
    sEq[t] = eqs; sUn[t] = uns;
    __syncthreads();
    for (int o = 128; o > 0; o >>= 1) {
        if (t < o) { sEq[t] += sEq[t + o]; sUn[t] += sUn[t + o]; }
        __syncthreads();
    }
    if (t == 0)
        partials[i * 512 + blockIdx.x] = make_float2(sEq[0], sUn[0]);
}

// ---- final reduce ----
__global__ void final_kernel(const float2* __restrict__ partials, float* __restrict__ out) {
    int t = threadIdx.x;                         // 256 threads, 2048 partials
    double acc = 0.0;
#pragma unroll
    for (int k = 0; k < 8; k++) {
        float2 p = partials[t + k * 256];
        acc += (double)p.x + (double)p.y;
    }
    __shared__ double sm[256];
    sm[t] = acc;
    __syncthreads();
    for (int o = 128; o > 0; o >>= 1) {
        if (t < o) sm[t] += sm[t + o];
        __syncthreads();
    }
    if (t == 0) {
        double denom = 4.0 * (double)SNUM;       // each mean over 4*S terms; ALPHA=1
        out[0] = (float)(sm[0] / denom / (double)NIMG);
    }
}

extern "C" void kernel_launch(void* const* d_in, const int* in_sizes, int n_in,
                              void* d_out, int out_size, void* d_ws, size_t ws_size,
                              hipStream_t stream) {
    const float* inputs  = (const float*)d_in[0];
    const float* targets = (const float*)d_in[1];
    const float* images  = (const float*)d_in[2];
    const int* ra = (const int*)d_in[3];
    const int* rd = (const int*)d_in[4];
    const int* rp = (const int*)d_in[5];
    float* out = (float*)d_out;

    char* ws = (char*)d_ws;
    int*      vtotG    = (int*)ws;                         // [4]
    float*    blockmax = (float*)(ws + 1024);              // [1024] = 4KB
    int*      blkV     = (int*)(ws + 16384);               // [12288] = 48KB
    int*      cntE     = (int*)(ws + 65536);               // [12288] = 48KB
    int*      SVg      = (int*)(ws + 114688);              // [12288] = 48KB
    float2*   partials = (float2*)(ws + 163840);           // [2048] = 16KB
    float2*   pairIT   = (float2*)(ws + 1048576);          // 25.2MB
    float2*   anchorSeg= (float2*)(ws + 26214400);         // 25.2MB (segmented)
    int*      compVSeg = (int*)(ws + 51380224);            // 12.6MB (segmented)
    // total ~61MB; every word written before read -> no memset needed

    void* args[] = {(void*)&inputs, (void*)&targets, (void*)&images,
                    (void*)&pairIT, (void*)&blockmax, (void*)&blkV, (void*)&cntE,
                    (void*)&anchorSeg, (void*)&compVSeg, (void*)&SVg, (void*)&vtotG};
    hipError_t cerr = hipLaunchCooperativeKernel(reinterpret_cast<void*>(fused_prep),
                                                 dim3(FPB), dim3(256), args, 0, stream);
    if (cerr != hipSuccess) {                    // fallback: same math, 2 plain dispatches
        (void)hipGetLastError();                 // clear sticky error
        prepA_kernel<<<FPB, 256, 0, stream>>>(inputs, targets, images,
                                              pairIT, compVSeg, blockmax, blkV);
        prepB_kernel<<<FPB, 256, 0, stream>>>(images, blockmax, blkV,
                                              anchorSeg, cntE, SVg, vtotG);
    }
    loss_kernel<<<dim3(512, NIMG), 256, 0, stream>>>(pairIT, anchorSeg, compVSeg,
                                                     cntE, SVg, vtotG,
                                                     ra, rd, rp, partials);
    final_kernel<<<1, 256, 0, stream>>>(partials, out);
}

// Round 10
// 180.106 us; speedup vs baseline: 1.8011x; 1.8011x over previous
//
#include <hip/hip_runtime.h>
#include <math.h>

#define W 1024
#define H 768
#define PIX (W*H)          // 786432
#define NIMG 4
#define SNUM 131072
#define BPI 3072           // 256-pixel units per image
#define NBP (NIMG*BPI)     // 12288 prep blocks
#define UPB 12             // units per compact block
#define NBC 1024           // compact blocks (256 per image)
#define MASKV (-1e-8f)

__device__ __forceinline__ void sobel_g(const float* __restrict__ img, int y, int x,
                                        float& gx, float& gy) {
    const float* r0 = img + (y - 1) * W + x;
    const float* r1 = r0 + W;
    const float* r2 = r1 + W;
    float a00 = r0[-1], a01 = r0[0], a02 = r0[1];
    float a10 = r1[-1],              a12 = r1[1];
    float a20 = r2[-1], a21 = r2[0], a22 = r2[1];
    gx = (a02 - a00) + 2.f * (a12 - a10) + (a22 - a20);
    gy = (a00 - a20) + 2.f * (a01 - a21) + (a02 - a22);
}

// ---- D0: Sobel magnitude + block max + pack {inp,tgt} + segmented compV ----
__global__ void prep_kernel(const float* __restrict__ inputs,
                            const float* __restrict__ targets,
                            const float* __restrict__ images,
                            float2* __restrict__ pairIT,
                            int* __restrict__ compVSeg,
                            float* __restrict__ blockmax,
                            int* __restrict__ blkV) {
    int b = blockIdx.x, t = threadIdx.x;
    int i = b / BPI, unit = b - i * BPI;
    int gp = unit * 256 + t;
    int y = gp >> 10, x = gp & (W - 1);
    const float* img = images + (size_t)i * 3 * PIX;   // channel 0
    float e = 0.f;
    if (y >= 1 && y <= H - 2 && x >= 1 && x <= W - 2) {
        float gx, gy;
        sobel_g(img, y, x, gx, gy);
        e = sqrtf(gx * gx + gy * gy);
    }
    size_t off = (size_t)i * PIX + gp;
    float inv = inputs[off], tgv = targets[off];
    pairIT[off] = make_float2(inv, tgv);

    int lane = t & 63, w = t >> 6;
    bool v = tgv > MASKV;
    unsigned long long mV = __ballot(v);
    __shared__ float sm[256];
    __shared__ int sW[4];
    if (lane == 0) sW[w] = __popcll(mV);
    sm[t] = e;
    __syncthreads();
    int base = 0;
    for (int q = 0; q < w; q++) base += sW[q];
    if (t == 0) blkV[b] = sW[0] + sW[1] + sW[2] + sW[3];
    if (v) compVSeg[off - t + base + __popcll(mV & ((1ull << lane) - 1ull))] = gp;
    for (int o = 128; o > 0; o >>= 1) {
        if (t < o) sm[t] = fmaxf(sm[t], sm[t + o]);
        __syncthreads();
    }
    if (t == 0) blockmax[b] = sm[0];
}

// ---- D1: redundant thr-reduce + segmented edge compaction + blkV scan ----
__global__ void compact_kernel(const float* __restrict__ images,
                               const float* __restrict__ blockmax,
                               const int* __restrict__ blkV,
                               float2* __restrict__ anchorSeg,
                               int* __restrict__ cntE,
                               int* __restrict__ SVg,
                               int* __restrict__ vtotG) {
    int blk = blockIdx.x, t = threadIdx.x;
    int i = blk >> 8, bb = blk & 255;
    const float* img = images + (size_t)i * 3 * PIX;
    int lane = t & 63, w = t >> 6;
    unsigned long long lm = (1ull << lane) - 1ull;

    // redundant per-image max reduce (3072 entries, L2-hot)
    __shared__ float sRed[256];
    __shared__ int sW2[4];
    const float* bm = blockmax + i * BPI;
    float mx = 0.f;
#pragma unroll
    for (int k = 0; k < 12; k++) mx = fmaxf(mx, bm[t + k * 256]);
    sRed[t] = mx;
    __syncthreads();
    for (int o = 128; o > 0; o >>= 1) {
        if (t < o) sRed[t] = fmaxf(sRed[t], sRed[t + o]);
        __syncthreads();
    }
    float thr = 0.1f * sRed[0];

    for (int k = 0; k < UPB; k++) {
        int unit = bb * UPB + k;
        int gp = unit * 256 + t;
        int y = gp >> 10, x = gp & (W - 1);
        float e = 0.f, gx = 0.f, gy = 0.f;
        bool inner = (y >= 1 && y <= H - 2 && x >= 1 && x <= W - 2);
        if (inner) { sobel_g(img, y, x, gx, gy); e = sqrtf(gx * gx + gy * gy); }
        bool isE = (e >= thr);                    // border e=0: matches padded ref
        unsigned long long mE = __ballot(isE);
        __syncthreads();                          // protect sW2 reuse across iterations
        if (lane == 0) sW2[w] = __popcll(mE);
        __syncthreads();
        int base = 0;
        for (int q = 0; q < w; q++) base += sW2[q];
        if (t == 0) cntE[i * BPI + unit] = sW2[0] + sW2[1] + sW2[2] + sW2[3];
        if (isE) {
            float th = inner ? atan2f(gy, gx) : 0.f;
            anchorSeg[(size_t)i * PIX + unit * 256 + base + __popcll(mE & lm)] =
                make_float2(__int_as_float(gp), th);
        }
    }

    if (bb == 0) {                                // per-image blkV scan -> SVg, vtotG
        __syncthreads();
        __shared__ int sT[256];
        const int* bv = blkV + i * BPI;
        int loc[12]; int tot = 0;
#pragma unroll
        for (int k = 0; k < 12; k++) { loc[k] = bv[t * 12 + k]; tot += loc[k]; }
        sT[t] = tot;
        __syncthreads();
        for (int o = 1; o < 256; o <<= 1) {
            int v = (t >= o) ? sT[t - o] : 0;
            __syncthreads();
            sT[t] += v;
            __syncthreads();
        }
        int run = sT[t] - tot;
        int* sv = SVg + i * BPI;
#pragma unroll
        for (int k = 0; k < 12; k++) { sv[t * 12 + k] = run; run += loc[k]; }
        if (t == 255) vtotG[i] = sT[255];
    }
}

// ---- D2: loss (round-7 verbatim: LDS scan of cntE + binary search) ----
__device__ __forceinline__ void pair_term(float2 a, float2 b, float& eqs, float& uns) {
    float cm = ((a.y > MASKV) ? 1.f : 0.f) * ((b.y > MASKV) ? 1.f : 0.f);
    float ratio = (a.y + 1e-6f) / (b.y + 1e-6f);
    const float HIv = 1.03f;
    const float LOv = (float)(1.0 / 1.03);
    bool eq = (ratio < HIv) && (ratio > LOv);
    if (eq) {
        float d = a.x - b.x;
        eqs += d * d * cm;
    } else {
        float label = ((ratio >= HIv) ? 1.f : 0.f) + ((ratio <= LOv) ? -1.f : 0.f);
        uns += log1pf(expf((b.x - a.x) * label)) * cm;
    }
}

__global__ void loss_kernel(const float2* __restrict__ pairIT,
                            const float2* __restrict__ anchorSeg,
                            const int* __restrict__ compVSeg,
                            const int* __restrict__ cntE,
                            const int* __restrict__ SVg,
                            const int* __restrict__ vtotG,
                            const int* __restrict__ ra, const int* __restrict__ rd,
                            const int* __restrict__ rp,
                            float2* __restrict__ partials) {
    int i = blockIdx.y, t = threadIdx.x;
    __shared__ int S[BPI];                       // 12KB: exclusive scan of cntE
    __shared__ int sT[256];
    {
        const int* ce = cntE + i * BPI;
        int loc[12]; int tot = 0;
#pragma unroll
        for (int k = 0; k < 12; k++) { loc[k] = ce[t * 12 + k]; tot += loc[k]; }
        sT[t] = tot;
        __syncthreads();
        for (int o = 1; o < 256; o <<= 1) {
            int v = (t >= o) ? sT[t - o] : 0;
            __syncthreads();
            sT[t] += v;
            __syncthreads();
        }
        int run = sT[t] - tot;
#pragma unroll
        for (int k = 0; k < 12; k++) { S[t * 12 + k] = run; run += loc[k]; }
        __syncthreads();
    }
    int eT = sT[255];                            // etot; >=1 always (emax passes thr)
    int vT = vtotG[i];
    int nval = (vT > 0) ? vT : 1;

    int s = blockIdx.x * 256 + t;
    const float2* pIT = pairIT + (size_t)i * PIX;

    int j = ra[(size_t)i * SNUM + s] % eT;
    int lo = 0, hi = BPI - 1;                    // largest b with S[b] <= j
#pragma unroll
    for (int k = 0; k < 12; k++) {
        int mid = (lo + hi + 1) >> 1;
        if (S[mid] <= j) lo = mid; else hi = mid - 1;
    }
    float2 ac = anchorSeg[(size_t)i * PIX + lo * 256 + (j - S[lo])];
    int anchor = __float_as_int(ac.x);
    float sv = sinf(ac.y), cv = cosf(ac.y);
    int row_a = anchor >> 10, col_a = anchor & (W - 1);

    int pix4[4];
#pragma unroll
    for (int k = 0; k < 4; k++) {
        int r = rd[((size_t)i * 4 + k) * SNUM + s];
        float dist = ((float)r + 2.0f) * ((k < 2) ? -1.f : 1.f);
        int cc = col_a + (int)rintf(dist * cv);  // round-half-even = jnp.round
        int rr = row_a + (int)rintf(dist * sv);
        cc = min(max(cc, 0), W - 1);
        rr = min(max(rr, 0), H - 1);
        pix4[k] = (rr << 10) | cc;
    }
    int2 rr2 = *(const int2*)(rp + (size_t)i * 2 * SNUM + 2 * s);
    int r0 = rr2.x % nval, r1 = rr2.y % nval;
    int A, B;
    if ((vT == PIX) || (vT == 0)) {              // identity compaction cases
        A = r0; B = r1;
    } else {
        const int* SV = SVg + i * BPI;
        int lo2 = 0, hi2 = BPI - 1;
        int lo3 = 0, hi3 = BPI - 1;
#pragma unroll
        for (int k = 0; k < 12; k++) {
            int m2 = (lo2 + hi2 + 1) >> 1;
            if (SV[m2] <= r0) lo2 = m2; else hi2 = m2 - 1;
            int m3 = (lo3 + hi3 + 1) >> 1;
            if (SV[m3] <= r1) lo3 = m3; else hi3 = m3 - 1;
        }
        A = compVSeg[(size_t)i * PIX + lo2 * 256 + (r0 - SV[lo2])];
        B = compVSeg[(size_t)i * PIX + lo3 * 256 + (r1 - SV[lo3])];
    }

    float2 a0 = pIT[pix4[0]], a1 = pIT[pix4[1]], a2 = pIT[pix4[2]], a3 = pIT[pix4[3]];
    float2 b0 = pIT[A], b1 = pIT[B];
    float eqs = 0.f, uns = 0.f;
    pair_term(a0, a1, eqs, uns);
    pair_term(a1, a2, eqs, uns);
    pair_term(a2, a3, eqs, uns);
    pair_term(b0, b1, eqs, uns);

    __shared__ float sEq[256], sUn[256];
    sEq[t] = eqs; sUn[t] = uns;
    __syncthreads();
    for (int o = 128; o > 0; o >>= 1) {
        if (t < o) { sEq[t] += sEq[t + o]; sUn[t] += sUn[t + o]; }
        __syncthreads();
    }
    if (t == 0)
        partials[i * 512 + blockIdx.x] = make_float2(sEq[0], sUn[0]);
}

// ---- D3: final reduce ----
__global__ void final_kernel(const float2* __restrict__ partials, float* __restrict__ out) {
    int t = threadIdx.x;                         // 256 threads, 2048 partials
    double acc = 0.0;
#pragma unroll
    for (int k = 0; k < 8; k++) {
        float2 p = partials[t + k * 256];
        acc += (double)p.x + (double)p.y;
    }
    __shared__ double sm[256];
    sm[t] = acc;
    __syncthreads();
    for (int o = 128; o > 0; o >>= 1) {
        if (t < o) sm[t] += sm[t + o];
        __syncthreads();
    }
    if (t == 0) {
        double denom = 4.0 * (double)SNUM;       // each mean over 4*S terms; ALPHA=1
        out[0] = (float)(sm[0] / denom / (double)NIMG);
    }
}

extern "C" void kernel_launch(void* const* d_in, const int* in_sizes, int n_in,
                              void* d_out, int out_size, void* d_ws, size_t ws_size,
                              hipStream_t stream) {
    const float* inputs  = (const float*)d_in[0];
    const float* targets = (const float*)d_in[1];
    const float* images  = (const float*)d_in[2];
    const int* ra = (const int*)d_in[3];
    const int* rd = (const int*)d_in[4];
    const int* rp = (const int*)d_in[5];
    float* out = (float*)d_out;

    char* ws = (char*)d_ws;
    int*      vtotG    = (int*)ws;                         // [4]
    float*    blockmax = (float*)(ws + 1024);              // [12288] = 48KB
    int*      blkV     = (int*)(ws + 50176);               // [12288] = 48KB
    int*      cntE     = (int*)(ws + 99328);               // [12288] = 48KB
    int*      SVg      = (int*)(ws + 148480);              // [12288] = 48KB
    float2*   partials = (float2*)(ws + 197632);           // [2048] = 16KB
    float2*   pairIT   = (float2*)(ws + 1048576);          // 25.2MB
    float2*   anchorSeg= (float2*)(ws + 26214400);         // 25.2MB (segmented)
    int*      compVSeg = (int*)(ws + 51380224);            // 12.6MB (segmented)
    // total ~61MB; every word written before read -> no memset needed

    prep_kernel<<<NBP, 256, 0, stream>>>(inputs, targets, images,
                                         pairIT, compVSeg, blockmax, blkV);
    compact_kernel<<<NBC, 256, 0, stream>>>(images, blockmax, blkV,
                                            anchorSeg, cntE, SVg, vtotG);
    loss_kernel<<<dim3(512, NIMG), 256, 0, stream>>>(pairIT, anchorSeg, compVSeg,
                                                     cntE, SVg, vtotG,
                                                     ra, rd, rp, partials);
    final_kernel<<<1, 256, 0, stream>>>(partials, out);
}

// Round 11
// 168.427 us; speedup vs baseline: 1.9260x; 1.0693x over previous
//
#include <hip/hip_runtime.h>
#include <hip/hip_fp16.h>
#include <math.h>

#define W 1024
#define H 768
#define PIX (W*H)          // 786432
#define NIMG 4
#define SNUM 131072
#define BPI 3072           // 256-pixel units per image
#define NBP (NIMG*BPI)     // 12288 prep blocks
#define UPB 12             // units per compact block
#define NBC 1024           // compact blocks (256 per image)
#define MASKV (-1e-8f)

__device__ __forceinline__ void sobel_g(const float* __restrict__ img, int y, int x,
                                        float& gx, float& gy) {
    const float* r0 = img + (y - 1) * W + x;
    const float* r1 = r0 + W;
    const float* r2 = r1 + W;
    float a00 = r0[-1], a01 = r0[0], a02 = r0[1];
    float a10 = r1[-1],              a12 = r1[1];
    float a20 = r2[-1], a21 = r2[0], a22 = r2[1];
    gx = (a02 - a00) + 2.f * (a12 - a10) + (a22 - a20);
    gy = (a00 - a20) + 2.f * (a01 - a21) + (a02 - a22);
}

// ---- D0: Sobel magnitude + block max + pack {inp,tgt} fp16 + valid counts ----
__global__ void prep_kernel(const float* __restrict__ inputs,
                            const float* __restrict__ targets,
                            const float* __restrict__ images,
                            __half2* __restrict__ pairIT,
                            float* __restrict__ blockmax,
                            int* __restrict__ blkV) {
    int b = blockIdx.x, t = threadIdx.x;
    int i = b / BPI, unit = b - i * BPI;
    int gp = unit * 256 + t;
    int y = gp >> 10, x = gp & (W - 1);
    const float* img = images + (size_t)i * 3 * PIX;   // channel 0
    float e = 0.f;
    if (y >= 1 && y <= H - 2 && x >= 1 && x <= W - 2) {
        float gx, gy;
        sobel_g(img, y, x, gx, gy);
        e = sqrtf(gx * gx + gy * gy);
    }
    size_t off = (size_t)i * PIX + gp;
    float inv = inputs[off], tgv = targets[off];
    __half2 h;
    h.x = __float2half_rn(inv);
    h.y = __float2half_rn(tgv);
    pairIT[off] = h;

    int lane = t & 63, w = t >> 6;
    unsigned long long mV = __ballot(tgv > MASKV);
    __shared__ float sm[256];
    __shared__ int sW[4];
    if (lane == 0) sW[w] = __popcll(mV);
    sm[t] = e;
    __syncthreads();
    if (t == 0) blkV[b] = sW[0] + sW[1] + sW[2] + sW[3];
    for (int o = 128; o > 0; o >>= 1) {
        if (t < o) sm[t] = fmaxf(sm[t], sm[t + o]);
        __syncthreads();
    }
    if (t == 0) blockmax[b] = sm[0];
}

// ---- D1: redundant thr/vtot reduce + segmented edge compaction + blkV scan ----
__global__ void compact_kernel(const float* __restrict__ images,
                               const float* __restrict__ targets,
                               const float* __restrict__ blockmax,
                               const int* __restrict__ blkV,
                               float2* __restrict__ anchorSeg,
                               int* __restrict__ compVSeg,
                               int* __restrict__ cntE,
                               int* __restrict__ SVg,
                               int* __restrict__ vtotG) {
    int blk = blockIdx.x, t = threadIdx.x;
    int i = blk >> 8, bb = blk & 255;
    const float* img = images + (size_t)i * 3 * PIX;
    int lane = t & 63, w = t >> 6;
    unsigned long long lm = (1ull << lane) - 1ull;

    // redundant per-image reduces: emax (max), vtot (sum) — 3072 entries each, L2-hot
    __shared__ float sRed[256];
    __shared__ int sRedI[256];
    __shared__ int sW2[4];
    const float* bm = blockmax + i * BPI;
    const int* bv = blkV + i * BPI;
    float mx = 0.f; int sv = 0;
#pragma unroll
    for (int k = 0; k < 12; k++) { mx = fmaxf(mx, bm[t + k * 256]); sv += bv[t + k * 256]; }
    sRed[t] = mx; sRedI[t] = sv;
    __syncthreads();
    for (int o = 128; o > 0; o >>= 1) {
        if (t < o) { sRed[t] = fmaxf(sRed[t], sRed[t + o]); sRedI[t] += sRedI[t + o]; }
        __syncthreads();
    }
    float thr = 0.1f * sRed[0];
    int vtotR = sRedI[0];

    for (int k = 0; k < UPB; k++) {
        int unit = bb * UPB + k;
        int gp = unit * 256 + t;
        int y = gp >> 10, x = gp & (W - 1);
        float e = 0.f, gx = 0.f, gy = 0.f;
        bool inner = (y >= 1 && y <= H - 2 && x >= 1 && x <= W - 2);
        if (inner) { sobel_g(img, y, x, gx, gy); e = sqrtf(gx * gx + gy * gy); }
        bool isE = (e >= thr);                    // border e=0: matches padded ref
        unsigned long long mE = __ballot(isE);
        __syncthreads();                          // protect sW2 reuse across iterations
        if (lane == 0) sW2[w] = __popcll(mE);
        __syncthreads();
        int base = 0;
        for (int q = 0; q < w; q++) base += sW2[q];
        if (t == 0) cntE[i * BPI + unit] = sW2[0] + sW2[1] + sW2[2] + sW2[3];
        if (isE) {
            float th = inner ? atan2f(gy, gx) : 0.f;
            anchorSeg[(size_t)i * PIX + unit * 256 + base + __popcll(mE & lm)] =
                make_float2(__int_as_float(gp), th);
        }
    }

    if (vtotR < PIX) {                            // general path only: segmented compV
        for (int k = 0; k < UPB; k++) {
            int unit = bb * UPB + k;
            int gp = unit * 256 + t;
            bool v = targets[(size_t)i * PIX + gp] > MASKV;
            unsigned long long mV = __ballot(v);
            __syncthreads();
            if (lane == 0) sW2[w] = __popcll(mV);
            __syncthreads();
            int base = 0;
            for (int q = 0; q < w; q++) base += sW2[q];
            if (v) compVSeg[(size_t)i * PIX + unit * 256 + base + __popcll(mV & lm)] = gp;
        }
    }

    if (bb == 0) {                                // per-image blkV scan -> SVg, vtotG
        __syncthreads();
        __shared__ int sT[256];
        int loc[12]; int tot = 0;
#pragma unroll
        for (int k = 0; k < 12; k++) { loc[k] = bv[t * 12 + k]; tot += loc[k]; }
        sT[t] = tot;
        __syncthreads();
        for (int o = 1; o < 256; o <<= 1) {
            int v = (t >= o) ? sT[t - o] : 0;
            __syncthreads();
            sT[t] += v;
            __syncthreads();
        }
        int run = sT[t] - tot;
        int* svp = SVg + i * BPI;
#pragma unroll
        for (int k = 0; k < 12; k++) { svp[t * 12 + k] = run; run += loc[k]; }
        if (t == 255) vtotG[i] = sT[255];
    }
}

// ---- D2: loss (fp16 gathers; LDS scan of cntE + binary search) ----
__device__ __forceinline__ void pair_term(float2 a, float2 b, float& eqs, float& uns) {
    float cm = ((a.y > MASKV) ? 1.f : 0.f) * ((b.y > MASKV) ? 1.f : 0.f);
    float ratio = (a.y + 1e-6f) / (b.y + 1e-6f);
    const float HIv = 1.03f;
    const float LOv = (float)(1.0 / 1.03);
    bool eq = (ratio < HIv) && (ratio > LOv);
    if (eq) {
        float d = a.x - b.x;
        eqs += d * d * cm;
    } else {
        float label = ((ratio >= HIv) ? 1.f : 0.f) + ((ratio <= LOv) ? -1.f : 0.f);
        uns += log1pf(expf((b.x - a.x) * label)) * cm;
    }
}

__device__ __forceinline__ float2 h2f(__half2 h) {
    return make_float2(__half2float(h.x), __half2float(h.y));
}

__global__ void loss_kernel(const __half2* __restrict__ pairIT,
                            const float2* __restrict__ anchorSeg,
                            const int* __restrict__ compVSeg,
                            const int* __restrict__ cntE,
                            const int* __restrict__ SVg,
                            const int* __restrict__ vtotG,
                            const int* __restrict__ ra, const int* __restrict__ rd,
                            const int* __restrict__ rp,
                            float2* __restrict__ partials) {
    int i = blockIdx.y, t = threadIdx.x;
    __shared__ int S[BPI];                       // 12KB: exclusive scan of cntE
    __shared__ int sT[256];
    {
        const int* ce = cntE + i * BPI;
        int loc[12]; int tot = 0;
#pragma unroll
        for (int k = 0; k < 12; k++) { loc[k] = ce[t * 12 + k]; tot += loc[k]; }
        sT[t] = tot;
        __syncthreads();
        for (int o = 1; o < 256; o <<= 1) {
            int v = (t >= o) ? sT[t - o] : 0;
            __syncthreads();
            sT[t] += v;
            __syncthreads();
        }
        int run = sT[t] - tot;
#pragma unroll
        for (int k = 0; k < 12; k++) { S[t * 12 + k] = run; run += loc[k]; }
        __syncthreads();
    }
    int eT = sT[255];                            // etot; >=1 always (emax passes thr)
    int vT = vtotG[i];
    int nval = (vT > 0) ? vT : 1;

    int s = blockIdx.x * 256 + t;
    const __half2* pIT = pairIT + (size_t)i * PIX;

    int j = ra[(size_t)i * SNUM + s] % eT;
    int lo = 0, hi = BPI - 1;                    // largest b with S[b] <= j
#pragma unroll
    for (int k = 0; k < 12; k++) {
        int mid = (lo + hi + 1) >> 1;
        if (S[mid] <= j) lo = mid; else hi = mid - 1;
    }
    float2 ac = anchorSeg[(size_t)i * PIX + lo * 256 + (j - S[lo])];
    int anchor = __float_as_int(ac.x);
    float sv = sinf(ac.y), cv = cosf(ac.y);
    int row_a = anchor >> 10, col_a = anchor & (W - 1);

    int pix4[4];
#pragma unroll
    for (int k = 0; k < 4; k++) {
        int r = rd[((size_t)i * 4 + k) * SNUM + s];
        float dist = ((float)r + 2.0f) * ((k < 2) ? -1.f : 1.f);
        int cc = col_a + (int)rintf(dist * cv);  // round-half-even = jnp.round
        int rr = row_a + (int)rintf(dist * sv);
        cc = min(max(cc, 0), W - 1);
        rr = min(max(rr, 0), H - 1);
        pix4[k] = (rr << 10) | cc;
    }
    int2 rr2 = *(const int2*)(rp + (size_t)i * 2 * SNUM + 2 * s);
    int r0 = rr2.x % nval, r1 = rr2.y % nval;
    int A, B;
    if ((vT == PIX) || (vT == 0)) {              // identity compaction cases
        A = r0; B = r1;
    } else {
        const int* SV = SVg + i * BPI;
        int lo2 = 0, hi2 = BPI - 1;
        int lo3 = 0, hi3 = BPI - 1;
#pragma unroll
        for (int k = 0; k < 12; k++) {
            int m2 = (lo2 + hi2 + 1) >> 1;
            if (SV[m2] <= r0) lo2 = m2; else hi2 = m2 - 1;
            int m3 = (lo3 + hi3 + 1) >> 1;
            if (SV[m3] <= r1) lo3 = m3; else hi3 = m3 - 1;
        }
        A = compVSeg[(size_t)i * PIX + lo2 * 256 + (r0 - SV[lo2])];
        B = compVSeg[(size_t)i * PIX + lo3 * 256 + (r1 - SV[lo3])];
    }

    float2 a0 = h2f(pIT[pix4[0]]), a1 = h2f(pIT[pix4[1]]);
    float2 a2 = h2f(pIT[pix4[2]]), a3 = h2f(pIT[pix4[3]]);
    float2 b0 = h2f(pIT[A]), b1 = h2f(pIT[B]);
    float eqs = 0.f, uns = 0.f;
    pair_term(a0, a1, eqs, uns);
    pair_term(a1, a2, eqs, uns);
    pair_term(a2, a3, eqs, uns);
    pair_term(b0, b1, eqs, uns);

    __shared__ float sEq[256], sUn[256];
    sEq[t] = eqs; sUn[t] = uns;
    __syncthreads();
    for (int o = 128; o > 0; o >>= 1) {
        if (t < o) { sEq[t] += sEq[t + o]; sUn[t] += sUn[t + o]; }
        __syncthreads();
    }
    if (t == 0)
        partials[i * 512 + blockIdx.x] = make_float2(sEq[0], sUn[0]);
}

// ---- D3: final reduce ----
__global__ void final_kernel(const float2* __restrict__ partials, float* __restrict__ out) {
    int t = threadIdx.x;                         // 256 threads, 2048 partials
    double acc = 0.0;
#pragma unroll
    for (int k = 0; k < 8; k++) {
        float2 p = partials[t + k * 256];
        acc += (double)p.x + (double)p.y;
    }
    __shared__ double sm[256];
    sm[t] = acc;
    __syncthreads();
    for (int o = 128; o > 0; o >>= 1) {
        if (t < o) sm[t] += sm[t + o];
        __syncthreads();
    }
    if (t == 0) {
        double denom = 4.0 * (double)SNUM;       // each mean over 4*S terms; ALPHA=1
        out[0] = (float)(sm[0] / denom / (double)NIMG);
    }
}

extern "C" void kernel_launch(void* const* d_in, const int* in_sizes, int n_in,
                              void* d_out, int out_size, void* d_ws, size_t ws_size,
                              hipStream_t stream) {
    const float* inputs  = (const float*)d_in[0];
    const float* targets = (const float*)d_in[1];
    const float* images  = (const float*)d_in[2];
    const int* ra = (const int*)d_in[3];
    const int* rd = (const int*)d_in[4];
    const int* rp = (const int*)d_in[5];
    float* out = (float*)d_out;

    char* ws = (char*)d_ws;
    int*      vtotG    = (int*)ws;                         // [4]
    float*    blockmax = (float*)(ws + 1024);              // [12288] = 48KB
    int*      blkV     = (int*)(ws + 50176);               // [12288] = 48KB
    int*      cntE     = (int*)(ws + 99328);               // [12288] = 48KB
    int*      SVg      = (int*)(ws + 148480);              // [12288] = 48KB
    float2*   partials = (float2*)(ws + 197632);           // [2048] = 16KB
    __half2*  pairIT   = (__half2*)(ws + 1048576);         // 12.6MB (fp16 packed)
    float2*   anchorSeg= (float2*)(ws + 14680064);         // 25.2MB (segmented)
    int*      compVSeg = (int*)(ws + 39845888);            // 12.6MB (segmented)
    // total ~53MB; compVSeg read only when written (vtot<PIX)

    prep_kernel<<<NBP, 256, 0, stream>>>(inputs, targets, images,
                                         pairIT, blockmax, blkV);
    compact_kernel<<<NBC, 256, 0, stream>>>(images, targets, blockmax, blkV,
                                            anchorSeg, compVSeg, cntE, SVg, vtotG);
    loss_kernel<<<dim3(512, NIMG), 256, 0, stream>>>(pairIT, anchorSeg, compVSeg,
                                                     cntE, SVg, vtotG,
                                                     ra, rd, rp, partials);
    final_kernel<<<1, 256, 0, stream>>>(partials, out);
}

// Round 12
// 166.125 us; speedup vs baseline: 1.9527x; 1.0139x over previous
//
#include <hip/hip_runtime.h>
#include <hip/hip_fp16.h>
#include <math.h>

#define W 1024
#define H 768
#define PIX (W*H)          // 786432
#define NIMG 4
#define SNUM 131072
#define BPI 3072           // 256-pixel units per image
#define NBP (NIMG*BPI)     // 12288 prep blocks
#define UPB 12             // units per compact block
#define NBC 1024           // compact blocks (256 per image)
#define MASKV (-1e-8f)

__device__ __forceinline__ void sobel_g(const float* __restrict__ img, int y, int x,
                                        float& gx, float& gy) {
    const float* r0 = img + (y - 1) * W + x;
    const float* r1 = r0 + W;
    const float* r2 = r1 + W;
    float a00 = r0[-1], a01 = r0[0], a02 = r0[1];
    float a10 = r1[-1],              a12 = r1[1];
    float a20 = r2[-1], a21 = r2[0], a22 = r2[1];
    gx = (a02 - a00) + 2.f * (a12 - a10) + (a22 - a20);
    gy = (a00 - a20) + 2.f * (a01 - a21) + (a02 - a22);
}

// ---- D0: Sobel magnitude + block max + pack {inp,tgt} fp16 + valid counts ----
__global__ void prep_kernel(const float* __restrict__ inputs,
                            const float* __restrict__ targets,
                            const float* __restrict__ images,
                            __half2* __restrict__ pairIT,
                            float* __restrict__ blockmax,
                            int* __restrict__ blkV) {
    int b = blockIdx.x, t = threadIdx.x;
    int i = b / BPI, unit = b - i * BPI;
    int gp = unit * 256 + t;
    int y = gp >> 10, x = gp & (W - 1);
    const float* img = images + (size_t)i * 3 * PIX;   // channel 0
    float e = 0.f;
    if (y >= 1 && y <= H - 2 && x >= 1 && x <= W - 2) {
        float gx, gy;
        sobel_g(img, y, x, gx, gy);
        e = sqrtf(gx * gx + gy * gy);
    }
    size_t off = (size_t)i * PIX + gp;
    float inv = inputs[off], tgv = targets[off];
    __half2 h;
    h.x = __float2half_rn(inv);
    h.y = __float2half_rn(tgv);
    pairIT[off] = h;

    int lane = t & 63, w = t >> 6;
    unsigned long long mV = __ballot(tgv > MASKV);
    __shared__ float sm[256];
    __shared__ int sW[4];
    if (lane == 0) sW[w] = __popcll(mV);
    sm[t] = e;
    __syncthreads();
    if (t == 0) blkV[b] = sW[0] + sW[1] + sW[2] + sW[3];
    for (int o = 128; o > 0; o >>= 1) {
        if (t < o) sm[t] = fmaxf(sm[t], sm[t + o]);
        __syncthreads();
    }
    if (t == 0) blockmax[b] = sm[0];
}

// ---- D1: redundant thr/vtot reduce + segmented edge compaction + blkV scan ----
__global__ void compact_kernel(const float* __restrict__ images,
                               const float* __restrict__ targets,
                               const float* __restrict__ blockmax,
                               const int* __restrict__ blkV,
                               float2* __restrict__ anchorSeg,
                               int* __restrict__ compVSeg,
                               int* __restrict__ cntE,
                               int* __restrict__ SVg,
                               int* __restrict__ vtotG) {
    int blk = blockIdx.x, t = threadIdx.x;
    int i = blk >> 8, bb = blk & 255;
    const float* img = images + (size_t)i * 3 * PIX;
    int lane = t & 63, w = t >> 6;
    unsigned long long lm = (1ull << lane) - 1ull;

    // redundant per-image reduces: emax (max), vtot (sum) — 3072 entries each, L2-hot
    __shared__ float sRed[256];
    __shared__ int sRedI[256];
    __shared__ int sW2[4];
    const float* bm = blockmax + i * BPI;
    const int* bv = blkV + i * BPI;
    float mx = 0.f; int sv = 0;
#pragma unroll
    for (int k = 0; k < 12; k++) { mx = fmaxf(mx, bm[t + k * 256]); sv += bv[t + k * 256]; }
    sRed[t] = mx; sRedI[t] = sv;
    __syncthreads();
    for (int o = 128; o > 0; o >>= 1) {
        if (t < o) { sRed[t] = fmaxf(sRed[t], sRed[t + o]); sRedI[t] += sRedI[t + o]; }
        __syncthreads();
    }
    float thr = 0.1f * sRed[0];
    int vtotR = sRedI[0];

    for (int k = 0; k < UPB; k++) {
        int unit = bb * UPB + k;
        int gp = unit * 256 + t;
        int y = gp >> 10, x = gp & (W - 1);
        float e = 0.f, gx = 0.f, gy = 0.f;
        bool inner = (y >= 1 && y <= H - 2 && x >= 1 && x <= W - 2);
        if (inner) { sobel_g(img, y, x, gx, gy); e = sqrtf(gx * gx + gy * gy); }
        bool isE = (e >= thr);                    // border e=0: matches padded ref
        unsigned long long mE = __ballot(isE);
        __syncthreads();                          // protect sW2 reuse across iterations
        if (lane == 0) sW2[w] = __popcll(mE);
        __syncthreads();
        int base = 0;
        for (int q = 0; q < w; q++) base += sW2[q];
        if (t == 0) cntE[i * BPI + unit] = sW2[0] + sW2[1] + sW2[2] + sW2[3];
        if (isE) {
            float th = inner ? atan2f(gy, gx) : 0.f;
            anchorSeg[(size_t)i * PIX + unit * 256 + base + __popcll(mE & lm)] =
                make_float2(__int_as_float(gp), th);
        }
    }

    if (vtotR < PIX) {                            // general path only: segmented compV
        for (int k = 0; k < UPB; k++) {
            int unit = bb * UPB + k;
            int gp = unit * 256 + t;
            bool v = targets[(size_t)i * PIX + gp] > MASKV;
            unsigned long long mV = __ballot(v);
            __syncthreads();
            if (lane == 0) sW2[w] = __popcll(mV);
            __syncthreads();
            int base = 0;
            for (int q = 0; q < w; q++) base += sW2[q];
            if (v) compVSeg[(size_t)i * PIX + unit * 256 + base + __popcll(mV & lm)] = gp;
        }
    }

    if (bb == 0) {                                // per-image blkV scan -> SVg, vtotG
        __syncthreads();
        __shared__ int sT[256];
        int loc[12]; int tot = 0;
#pragma unroll
        for (int k = 0; k < 12; k++) { loc[k] = bv[t * 12 + k]; tot += loc[k]; }
        sT[t] = tot;
        __syncthreads();
        for (int o = 1; o < 256; o <<= 1) {
            int v = (t >= o) ? sT[t - o] : 0;
            __syncthreads();
            sT[t] += v;
            __syncthreads();
        }
        int run = sT[t] - tot;
        int* svp = SVg + i * BPI;
#pragma unroll
        for (int k = 0; k < 12; k++) { svp[t * 12 + k] = run; run += loc[k]; }
        if (t == 255) vtotG[i] = sT[255];
    }
}

// ---- D2: loss (fp16 gathers, XCD-affine: image = blockIdx & 3 -> XCDs {i, i+4}) ----
__device__ __forceinline__ void pair_term(float2 a, float2 b, float& eqs, float& uns) {
    float cm = ((a.y > MASKV) ? 1.f : 0.f) * ((b.y > MASKV) ? 1.f : 0.f);
    float ratio = (a.y + 1e-6f) / (b.y + 1e-6f);
    const float HIv = 1.03f;
    const float LOv = (float)(1.0 / 1.03);
    bool eq = (ratio < HIv) && (ratio > LOv);
    if (eq) {
        float d = a.x - b.x;
        eqs += d * d * cm;
    } else {
        float label = ((ratio >= HIv) ? 1.f : 0.f) + ((ratio <= LOv) ? -1.f : 0.f);
        uns += log1pf(expf((b.x - a.x) * label)) * cm;
    }
}

__device__ __forceinline__ float2 h2f(__half2 h) {
    return make_float2(__half2float(h.x), __half2float(h.y));
}

__global__ void loss_kernel(const __half2* __restrict__ pairIT,
                            const float2* __restrict__ anchorSeg,
                            const int* __restrict__ compVSeg,
                            const int* __restrict__ cntE,
                            const int* __restrict__ SVg,
                            const int* __restrict__ vtotG,
                            const int* __restrict__ ra, const int* __restrict__ rd,
                            const int* __restrict__ rp,
                            float2* __restrict__ partials) {
    int b = blockIdx.x, t = threadIdx.x;
    // XCD affinity: round-robin dispatch puts block b on XCD b%8; image = b&3 pins
    // image i to XCDs {i, i+4}. fp16 slice (3.15MB) fits each 4MB XCD L2.
    // Wrong mapping => perf-neutral, never incorrect.
    int i = b & 3;
    int sub = b >> 2;                            // [0, 512) within image
    __shared__ int S[BPI];                       // 12KB: exclusive scan of cntE
    __shared__ int sT[256];
    {
        const int* ce = cntE + i * BPI;
        int loc[12]; int tot = 0;
#pragma unroll
        for (int k = 0; k < 12; k++) { loc[k] = ce[t * 12 + k]; tot += loc[k]; }
        sT[t] = tot;
        __syncthreads();
        for (int o = 1; o < 256; o <<= 1) {
            int v = (t >= o) ? sT[t - o] : 0;
            __syncthreads();
            sT[t] += v;
            __syncthreads();
        }
        int run = sT[t] - tot;
#pragma unroll
        for (int k = 0; k < 12; k++) { S[t * 12 + k] = run; run += loc[k]; }
        __syncthreads();
    }
    int eT = sT[255];                            // etot; >=1 always (emax passes thr)
    int vT = vtotG[i];
    int nval = (vT > 0) ? vT : 1;

    int s = sub * 256 + t;
    const __half2* pIT = pairIT + (size_t)i * PIX;

    int j = ra[(size_t)i * SNUM + s] % eT;
    int lo = 0, hi = BPI - 1;                    // largest b with S[b] <= j
#pragma unroll
    for (int k = 0; k < 12; k++) {
        int mid = (lo + hi + 1) >> 1;
        if (S[mid] <= j) lo = mid; else hi = mid - 1;
    }
    float2 ac = anchorSeg[(size_t)i * PIX + lo * 256 + (j - S[lo])];
    int anchor = __float_as_int(ac.x);
    float sv = sinf(ac.y), cv = cosf(ac.y);
    int row_a = anchor >> 10, col_a = anchor & (W - 1);

    int pix4[4];
#pragma unroll
    for (int k = 0; k < 4; k++) {
        int r = rd[((size_t)i * 4 + k) * SNUM + s];
        float dist = ((float)r + 2.0f) * ((k < 2) ? -1.f : 1.f);
        int cc = col_a + (int)rintf(dist * cv);  // round-half-even = jnp.round
        int rr = row_a + (int)rintf(dist * sv);
        cc = min(max(cc, 0), W - 1);
        rr = min(max(rr, 0), H - 1);
        pix4[k] = (rr << 10) | cc;
    }
    int2 rr2 = *(const int2*)(rp + (size_t)i * 2 * SNUM + 2 * s);
    int r0 = rr2.x % nval, r1 = rr2.y % nval;
    int A, B;
    if ((vT == PIX) || (vT == 0)) {              // identity compaction cases
        A = r0; B = r1;
    } else {
        const int* SV = SVg + i * BPI;
        int lo2 = 0, hi2 = BPI - 1;
        int lo3 = 0, hi3 = BPI - 1;
#pragma unroll
        for (int k = 0; k < 12; k++) {
            int m2 = (lo2 + hi2 + 1) >> 1;
            if (SV[m2] <= r0) lo2 = m2; else hi2 = m2 - 1;
            int m3 = (lo3 + hi3 + 1) >> 1;
            if (SV[m3] <= r1) lo3 = m3; else hi3 = m3 - 1;
        }
        A = compVSeg[(size_t)i * PIX + lo2 * 256 + (r0 - SV[lo2])];
        B = compVSeg[(size_t)i * PIX + lo3 * 256 + (r1 - SV[lo3])];
    }

    float2 a0 = h2f(pIT[pix4[0]]), a1 = h2f(pIT[pix4[1]]);
    float2 a2 = h2f(pIT[pix4[2]]), a3 = h2f(pIT[pix4[3]]);
    float2 b0 = h2f(pIT[A]), b1 = h2f(pIT[B]);
    float eqs = 0.f, uns = 0.f;
    pair_term(a0, a1, eqs, uns);
    pair_term(a1, a2, eqs, uns);
    pair_term(a2, a3, eqs, uns);
    pair_term(b0, b1, eqs, uns);

    __shared__ float sEq[256], sUn[256];
    sEq[t] = eqs; sUn[t] = uns;
    __syncthreads();
    for (int o = 128; o > 0; o >>= 1) {
        if (t < o) { sEq[t] += sEq[t + o]; sUn[t] += sUn[t + o]; }
        __syncthreads();
    }
    if (t == 0)
        partials[b] = make_float2(sEq[0], sUn[0]);
}

// ---- D3: final reduce ----
__global__ void final_kernel(const float2* __restrict__ partials, float* __restrict__ out) {
    int t = threadIdx.x;                         // 256 threads, 2048 partials
    double acc = 0.0;
#pragma unroll
    for (int k = 0; k < 8; k++) {
        float2 p = partials[t + k * 256];
        acc += (double)p.x + (double)p.y;
    }
    __shared__ double sm[256];
    sm[t] = acc;
    __syncthreads();
    for (int o = 128; o > 0; o >>= 1) {
        if (t < o) sm[t] += sm[t + o];
        __syncthreads();
    }
    if (t == 0) {
        double denom = 4.0 * (double)SNUM;       // each mean over 4*S terms; ALPHA=1
        out[0] = (float)(sm[0] / denom / (double)NIMG);
    }
}

extern "C" void kernel_launch(void* const* d_in, const int* in_sizes, int n_in,
                              void* d_out, int out_size, void* d_ws, size_t ws_size,
                              hipStream_t stream) {
    const float* inputs  = (const float*)d_in[0];
    const float* targets = (const float*)d_in[1];
    const float* images  = (const float*)d_in[2];
    const int* ra = (const int*)d_in[3];
    const int* rd = (const int*)d_in[4];
    const int* rp = (const int*)d_in[5];
    float* out = (float*)d_out;

    char* ws = (char*)d_ws;
    int*      vtotG    = (int*)ws;                         // [4]
    float*    blockmax = (float*)(ws + 1024);              // [12288] = 48KB
    int*      blkV     = (int*)(ws + 50176);               // [12288] = 48KB
    int*      cntE     = (int*)(ws + 99328);               // [12288] = 48KB
    int*      SVg      = (int*)(ws + 148480);              // [12288] = 48KB
    float2*   partials = (float2*)(ws + 197632);           // [2048] = 16KB
    __half2*  pairIT   = (__half2*)(ws + 1048576);         // 12.6MB (fp16 packed)
    float2*   anchorSeg= (float2*)(ws + 14680064);         // 25.2MB (segmented)
    int*      compVSeg = (int*)(ws + 39845888);            // 12.6MB (segmented)
    // total ~53MB; compVSeg read only when written (vtot<PIX)

    prep_kernel<<<NBP, 256, 0, stream>>>(inputs, targets, images,
                                         pairIT, blockmax, blkV);
    compact_kernel<<<NBC, 256, 0, stream>>>(images, targets, blockmax, blkV,
                                            anchorSeg, compVSeg, cntE, SVg, vtotG);
    loss_kernel<<<2048, 256, 0, stream>>>(pairIT, anchorSeg, compVSeg,
                                          cntE, SVg, vtotG,
                                          ra, rd, rp, partials);
    final_kernel<<<1, 256, 0, stream>>>(partials, out);
}